// Round 13
// baseline (638.155 us; speedup 1.0000x reference)
//
#include <hip/hip_runtime.h>

#define NXI 384
#define NG  (NXI*NXI)          // 147456 elements per system
#define NSYS 8
#define BPS 32                 // blocks per system
#define NBLK (NSYS*BPS)        // 256 blocks
#define NTHR 512               // 8 waves/CU
#define ROWS_PB 12             // rows per block
#define EPB (ROWS_PB*NXI)      // 4608 elements per block
#define EPT (EPB/NTHR)         // 9 elements per thread

// thr = EPS*NX*NY = 1e-9*147456
#define THRC 1.47456e-4f

// ---- relaxed agent-scope accessors ----
__device__ __forceinline__ float aloadf(const float* p) {
  return __hip_atomic_load(p, __ATOMIC_RELAXED, __HIP_MEMORY_SCOPE_AGENT);
}
__device__ __forceinline__ void astoref(float* p, float v) {
  __hip_atomic_store(p, v, __ATOMIC_RELAXED, __HIP_MEMORY_SCOPE_AGENT);
}
__device__ __forceinline__ double aloadd(const double* p) {
  return __hip_atomic_load(p, __ATOMIC_RELAXED, __HIP_MEMORY_SCOPE_AGENT);
}
__device__ __forceinline__ void astored(double* p, double v) {
  __hip_atomic_store(p, v, __ATOMIC_RELAXED, __HIP_MEMORY_SCOPE_AGENT);
}

__device__ __forceinline__ double wave_red(double v) {
#pragma unroll
  for (int off = 32; off > 0; off >>= 1) v += __shfl_down(v, off, 64);
  return v;
}

// ---- per-system flag barrier: contention-free, no RMW (validated r7-r12) ----
__device__ __forceinline__ void sys_bar(unsigned* flags, unsigned* phase, int tid, int bs) {
  __atomic_signal_fence(__ATOMIC_SEQ_CST);
  __builtin_amdgcn_s_waitcnt(0);
  __syncthreads();
  const unsigned ph = ++(*phase);
  if (tid == 0) {
    __hip_atomic_store(flags + bs, ph, __ATOMIC_RELAXED, __HIP_MEMORY_SCOPE_AGENT);
  }
  if (tid < 64) {
    while (true) {
      const unsigned f = __hip_atomic_load(flags + (tid & 31), __ATOMIC_RELAXED,
                                           __HIP_MEMORY_SCOPE_AGENT);
      if (__ballot(f >= ph) == ~0ull) break;
      __builtin_amdgcn_s_sleep(1);
    }
  }
  __syncthreads();
  __atomic_signal_fence(__ATOMIC_SEQ_CST);
}

// Block-reduce n<=14 doubles, agent-store to channels [chan0..][sys][bs].
__device__ __forceinline__ void bredN(const double* v, int n,
                                      double* slots, int chan0,
                                      int sys, int bs, int tid) {
  __shared__ double sred[NTHR/64][14];
  const int wid = tid >> 6, lane = tid & 63;
#pragma unroll
  for (int q = 0; q < n; q++) {
    const double w = wave_red(v[q]);
    if (lane == 0) sred[wid][q] = w;
  }
  __syncthreads();
  if (tid == 0) {
#pragma unroll
    for (int q = 0; q < n; q++) {
      double a = 0.0;
#pragma unroll
      for (int w2 = 0; w2 < NTHR/64; w2++) a += sred[w2][q];
      astored(slots + (size_t)(chan0 + q) * NBLK + sys * BPS + bs, a);
    }
  }
  __syncthreads();
}

// Butterfly sums of n channels (bit-exact identical in every lane/block).
__device__ __forceinline__ void shredN(const double* slots, int chan0, int n,
                                       int sys, int lane, double* out) {
  double v[14];
#pragma unroll
  for (int q = 0; q < n; q++)
    v[q] = aloadd(slots + (size_t)(chan0 + q) * NBLK + sys * BPS + (lane & 31));
#pragma unroll
  for (int q = 0; q < n; q++) {
    double x = v[q];
    x += __shfl_xor(x, 1, 64);
    x += __shfl_xor(x, 2, 64);
    x += __shfl_xor(x, 4, 64);
    x += __shfl_xor(x, 8, 64);
    x += __shfl_xor(x, 16, 64);
    out[q] = x;
  }
}

__device__ __forceinline__ float froguard(double sq) {
  return sq > 0.0 ? (float)sqrt(sq) : 0.0f;
}

// ---- coefficient builders (bit-exact shared op sequences, validated r9-r11) ----
__device__ __forceinline__ float calc_d1b(const float* Vb, const float* M1b, int i, int j) {
  const int a0 = (i - 1 < 0) ? 0 : i - 1;
  const float vc = Vb[j * NXI + i] + 1.0f;
  const float vu = Vb[j * NXI + a0] + 1.0f;
  return M1b[j * NXI + a0] * ((vc - vu) / (0.5f * (vc + vu)));
}
__device__ __forceinline__ float calc_d2b(const float* Vb, const float* M2b, int i, int j) {
  const int b0 = (j - 1 < 0) ? 0 : j - 1;
  const float vc = Vb[j * NXI + i] + 1.0f;
  const float vl = Vb[b0 * NXI + i] + 1.0f;
  return M2b[b0 * NXI + i] * ((vc - vl) / (0.5f * (vc + vl)));
}

// 5-point stencil. Coeffs: bmo rows -1..13, bom rows -1..12 at (r+1)*NXI.
// bpo(i,j)=-20-bmo(i+1,j) (-10 at i=383); bop(i,j)=-20-bom(i,j+1) (-10 at j=383);
// boo = 81 + bmo + bom + bpo + bop (exact identities). src rows -2..13 at (r+2)*NXI.
__device__ __forceinline__ float applyA(const float* src, int r, int c, int gr,
                                        const float* cbmo, const float* cbom) {
  const int ci = (r + 1) * NXI + c;
  const int si = (r + 2) * NXI + c;
  const float uc = src[si];
  const float um = (gr == 0)       ? uc : src[si - NXI];
  const float ud = (gr == NXI - 1) ? uc : src[si + NXI];
  const float ul = (c == 0)        ? uc : src[si - 1];
  const float ur = (c == NXI - 1)  ? uc : src[si + 1];
  const float bmo = cbmo[ci], bom = cbom[ci];
  const float bpo = (gr < NXI - 1) ? (-20.0f - cbmo[ci + NXI]) : -10.0f;
  const float bop = (c < NXI - 1)  ? (-20.0f - cbom[ci + 1])   : -10.0f;
  const float boo = 81.0f + bmo + bom + bpo + bop;
  return boo * uc + bmo * um + bom * ul + bop * ur + bpo * ud;
}

// rowsum from stored coeffs (rows -1..12)
__device__ __forceinline__ float coeff_sum_stored(int r, int c, int gr,
                                                  const float* cbmo, const float* cbom) {
  const int ci = (r + 1) * NXI + c;
  const float bmo = cbmo[ci], bom = cbom[ci];
  const float bpo = (gr < NXI - 1) ? (-20.0f - cbmo[ci + NXI]) : -10.0f;
  const float bop = (c < NXI - 1)  ? (-20.0f - cbom[ci + 1])   : -10.0f;
  const float boo = 81.0f + bmo + bom + bpo + bop;
  return boo + bmo + bom + bpo + bop;
}
// same rowsum mirrored op-for-op from V/M (rows -2,13; validated r9-r11)
__device__ __forceinline__ float coeff_sum_direct(const float* Vb, const float* M1b,
                                                  const float* M2b, int gr, int c) {
  const float bmo = -10.0f - 5.0f * calc_d1b(Vb, M1b, gr, c);
  const float bom = -10.0f - 5.0f * calc_d2b(Vb, M2b, gr, c);
  float bpo;
  if (gr < NXI - 1) {
    const float bmon = -10.0f - 5.0f * calc_d1b(Vb, M1b, gr + 1, c);
    bpo = -20.0f - bmon;
  } else bpo = -10.0f;
  float bop;
  if (c < NXI - 1) {
    const float bomn = -10.0f - 5.0f * calc_d2b(Vb, M2b, gr, c + 1);
    bop = -20.0f - bomn;
  } else bop = -10.0f;
  const float boo = 81.0f + bmo + bom + bpo + bop;
  return boo + bmo + bom + bpo + bop;
}

__global__ __launch_bounds__(NTHR, 1) void bicg_kernel(
    const float* __restrict__ V, const float* __restrict__ M1, const float* __restrict__ M2,
    float* __restrict__ xout, float* __restrict__ wsf) {
  const int blk = blockIdx.x;
  const int sys = blk & (NSYS - 1);
  const int bs  = blk >> 3;
  const int tid = threadIdx.x;
  const int lane = tid & 63;
  const int gr0 = bs * ROWS_PB;

  // ---- LDS (~113 KB) ----
  __shared__ float slabP[16 * NXI];     // p rows -2..13
  __shared__ float slabV[16 * NXI];     // v rows -2..13 (x staging in restart)
  __shared__ float cbmo[15 * NXI];      // rows -1..13
  __shared__ float cbom[14 * NXI];      // rows -1..12
  __shared__ float rgh[4 * NXI];        // r ghosts rows -2,-1,12,13 (recursive)
  __shared__ float wgh[4 * NXI];        // w ghosts (refreshed every iter)
  __shared__ float ugh[4 * NXI];        // u = beta*(v - omega*w) ghosts (recursive)
  __shared__ float bcf[4];              // 0:alpha 1:omega 2:beta 3:r_abs
  __shared__ int   bci[1];              // 0 normal, 1 RES, 2 C3, 3 SKIP
  __shared__ float sh_r0abs;

  // ---- workspace ----
  unsigned* flags = (unsigned*)wsf + sys * 32;
  double* slots = (double*)(wsf + 1024);                // 32 chans * 256 doubles
  const size_t PSZ = (size_t)NSYS * BPS * 2 * NXI;
  float* gbase = wsf + 32768;
  float* ghv = gbase;                                    // [2(par)][sys][bs][2][NXI]
  float* ghw = ghv + 2 * PSZ;
  float* ghx = ghw + 2 * PSZ;                            // restart x halos [sys][bs][2][NXI]
  float* ghq = ghx + PSZ;                                // restart p halos [sys][bs][4][NXI]
  float* ghx_sys = ghx + (size_t)sys * BPS * 2 * NXI;
  float* ghq_sys = ghq + (size_t)sys * BPS * 4 * NXI;
  float* ghx_own = ghx_sys + (size_t)bs * 2 * NXI;
  float* ghq_own = ghq_sys + (size_t)bs * 4 * NXI;

  unsigned bphase = 0;

  const size_t so = (size_t)sys * NG;
  const float* Vb  = V  + so;
  const float* M1b = M1 + so;
  const float* M2b = M2 + so;
  float* xs = xout + so + (size_t)bs * EPB;

  // ---------- Phase 0: coefficients + V-mean partial ----------
  for (int q = tid; q < 15 * NXI; q += NTHR) {
    const int r = q / NXI - 1;                 // -1..13
    const int gr = gr0 + r;
    if ((unsigned)gr >= (unsigned)NXI) continue;
    const int c = q - (r + 1) * NXI;
    cbmo[q] = -10.0f - 5.0f * calc_d1b(Vb, M1b, gr, c);
    if (r <= 12) cbom[q] = -10.0f - 5.0f * calc_d2b(Vb, M2b, gr, c);
  }
  {
    double vsum = 0.0;
#pragma unroll
    for (int k = 0; k < EPT; k++) vsum += (double)Vb[bs * EPB + tid + k * NTHR];
    bredN(&vsum, 1, slots, 31, sys, bs, tid);
  }
  sys_bar(flags, &bphase, tid, bs);  // S0

  // ---------- Init: x=mb; p=r=r0 = mb - rowsum*mb; u = 0 ----------
  double smb[1]; shredN(slots, 31, 1, sys, lane, smb);
  const float mb = (float)(smb[0] / (double)NG) + 1.0f;
  float preg[EPT], rreg[EPT], r0reg[EPT], vreg[EPT], wreg[EPT], zreg[EPT], ureg[EPT], xreg[EPT];
#pragma unroll
  for (int k = 0; k < EPT; k++) {
    const int e = tid + k * NTHR;
    const int lr = e / NXI, c = e - lr * NXI;
    const float pn = mb - coeff_sum_stored(lr, c, gr0 + lr, cbmo, cbom) * mb;
    xreg[k] = mb;
    preg[k] = pn; rreg[k] = pn; r0reg[k] = pn;
    ureg[k] = 0.0f;
    slabP[(lr + 2) * NXI + c] = pn;
  }
  for (int g = tid; g < 4 * NXI; g += NTHR) {
    const int gi = g / NXI, c = g - gi * NXI;
    const int r = (gi < 2) ? gi - 2 : gi + 10;      // -2,-1,12,13
    ugh[g] = 0.0f;
    if ((r < 0) ? (bs > 0) : (bs < BPS - 1)) {
      const int gr = gr0 + r;
      const float rs = (r == -2 || r == 13)
          ? coeff_sum_direct(Vb, M1b, M2b, gr, c)
          : coeff_sum_stored(r, c, gr, cbmo, cbom);
      const float pn = mb - rs * mb;
      slabP[(r + 2) * NXI + c] = pn;
      rgh[g] = pn;
    }
  }
  if (tid == 0) { bcf[3] = 1.0f; bci[0] = 0; }

  for (int it = 0; it < 30; ++it) {
    __syncthreads();                 // bc + slab writes visible
    if (!(bcf[3] > THRC)) break;     // uniform (LDS broadcast)
    const int par = it & 1;
    float* ghv_sys = ghv + (size_t)par * PSZ + (size_t)sys * BPS * 2 * NXI;
    float* ghw_sys = ghw + (size_t)par * PSZ + (size_t)sys * BPS * 2 * NXI;
    float* ghv_own = ghv_sys + (size_t)bs * 2 * NXI;  // [0]=row1, [NXI]=row10
    float* ghw_own = ghw_sys + (size_t)bs * 2 * NXI;
    const int ch0 = par * 14;

    double d[14] = {0,0,0,0,0,0,0,0,0,0,0,0,0,0};
    // ==== pass A: v = A p (own + ghost -1,12); z = v - u; d[0..4] ====
#pragma unroll
    for (int k = 0; k < EPT; k++) {
      const int e = tid + k * NTHR;
      const int lr = e / NXI, c = e - lr * NXI;
      const float vv = applyA(slabP, lr, c, gr0 + lr, cbmo, cbom);
      vreg[k] = vv;
      zreg[k] = vv - ureg[k];             // z = A r by linearity recursion
      slabV[(lr + 2) * NXI + c] = vv;
      if (lr == 1)  astoref(ghv_own + c, vv);
      if (lr == 10) astoref(ghv_own + NXI + c, vv);
      d[0] += (double)vv * (double)r0reg[k];
      d[1] += (double)vv * (double)vv;
      d[2] += (double)rreg[k] * (double)r0reg[k];
      d[3] += (double)rreg[k] * (double)vv;
      d[4] += (double)rreg[k] * (double)rreg[k];
    }
    for (int g = tid; g < 2 * NXI; g += NTHR) {      // v ghosts rows -1,12
      const bool top = g < NXI;
      if (top ? (bs > 0) : (bs < BPS - 1)) {
        const int c = top ? g : g - NXI;
        const int r = top ? -1 : 12;
        slabV[(r + 2) * NXI + c] = applyA(slabP, r, c, gr0 + r, cbmo, cbom);
      }
    }
    __syncthreads();   // slabV rows -1..12 ready for pass B
    // ==== pass B: w = A v (own); d[5..13] ====
#pragma unroll
    for (int k = 0; k < EPT; k++) {
      const int e = tid + k * NTHR;
      const int lr = e / NXI, c = e - lr * NXI;
      const float ww = applyA(slabV, lr, c, gr0 + lr, cbmo, cbom);
      wreg[k] = ww;
      if (lr == 1)  astoref(ghw_own + c, ww);
      if (lr == 10) astoref(ghw_own + NXI + c, ww);
      const float zz = zreg[k];
      d[5]  += (double)zz * (double)zz;
      d[6]  += (double)zz * (double)ww;
      d[7]  += (double)ww * (double)ww;
      d[8]  += (double)zz * (double)rreg[k];
      d[9]  += (double)zz * (double)vreg[k];
      d[10] += (double)ww * (double)rreg[k];
      d[11] += (double)ww * (double)vreg[k];
      d[12] += (double)zz * (double)r0reg[k];
      d[13] += (double)ww * (double)r0reg[k];
    }
    bredN(d, 14, slots, ch0, sys, bs, tid);   // single fused reduction
    sys_bar(flags, &bphase, tid, bs);  // THE barrier

    // ==== post-barrier: wave0 scalars; waves 1-7 receive v,w rows -2,13 ====
    if (tid < 64) {
      double s[14];
      shredN(slots, ch0, 14, sys, lane, s);
      const float sigma = (float)s[0];
      const float v_abs = froguard(s[1]);
      const float rho_l = (float)s[2];
      const float r0a = (it == 0) ? froguard(s[4]) : sh_r0abs;
      int code = 0;
      float al = 0.f, om = 0.f, be = 0.f, ra = 0.f;
      if (it == 0 && !(r0a > THRC)) {
        code = 3; ra = r0a;
      } else if (sigma <= 1e-9f * v_abs * r0a) {
        code = 1;
      } else {
        al = rho_l / sigma;
        const double da = (double)al;
        const double ss2 = s[4] - 2.0 * da * s[3] + da * da * s[1];
        const float s_abs = froguard(ss2);
        if (s_abs <= THRC) {
          code = 2; ra = s_abs;
        } else {
          const double tt  = s[5] - 2.0 * da * s[6] + da * da * s[7];
          const double ts  = s[8] - da * s[9] - da * s[10] + da * da * s[11];
          const double sr0 = s[2] - da * s[0];
          const double tr0 = s[12] - da * s[13];
          om = (float)ts / (float)tt;
          const double dw = (double)om;
          const float rho_new = (float)(sr0 - dw * tr0);
          const double rr_new = ss2 - 2.0 * dw * ts + dw * dw * tt;
          be = (al / om) * (rho_new / rho_l);
          ra = froguard(rr_new);
        }
      }
      if (lane == 0) {
        bcf[0] = al; bcf[1] = om; bcf[2] = be; bcf[3] = ra; bci[0] = code;
        if (it == 0) sh_r0abs = r0a;
      }
    } else {
      for (int g = tid - 64; g < 2 * NXI; g += NTHR - 64) {  // v,w rows -2,13
        const bool top = g < NXI;
        const int c = top ? g : g - NXI;
        if (top) { if (bs > 0) {
          const size_t nb = (size_t)(bs - 1) * 2 * NXI;
          slabV[c] = aloadf(ghv_sys + nb + NXI + c);
          wgh[c]   = aloadf(ghw_sys + nb + NXI + c);
        }} else { if (bs < BPS - 1) {
          const size_t nb = (size_t)(bs + 1) * 2 * NXI;
          slabV[15 * NXI + c] = aloadf(ghv_sys + nb + c);
          wgh[3 * NXI + c]    = aloadf(ghw_sys + nb + c);
        }}
      }
    }
    __syncthreads();
    const int code = bci[0];

    if (code == 3) continue;          // converged at init: x stays mb; top breaks

    if (code == 1) {
      // ---- restart: p = r = r0 = mb - A x ; u = 0 ----
#pragma unroll
      for (int k = 0; k < EPT; k++) {
        const int e = tid + k * NTHR;
        const int lr = e / NXI, c = e - lr * NXI;
        slabV[(lr + 2) * NXI + c] = xreg[k];
        if (lr == 0)  astoref(ghx_own + c, xreg[k]);
        if (lr == 11) astoref(ghx_own + NXI + c, xreg[k]);
      }
      sys_bar(flags, &bphase, tid, bs);  // R1
      for (int g = tid; g < 2 * NXI; g += NTHR) {
        const bool top = g < NXI;
        const int c = top ? g : g - NXI;
        if (top) { if (bs > 0)       slabV[1 * NXI + c]  = aloadf(ghx_sys + (size_t)(bs - 1) * 2 * NXI + NXI + c); }
        else     { if (bs < BPS - 1) slabV[14 * NXI + c] = aloadf(ghx_sys + (size_t)(bs + 1) * 2 * NXI + c); }
      }
      __syncthreads();
      double pp = 0;
#pragma unroll
      for (int k = 0; k < EPT; k++) {
        const int e = tid + k * NTHR;
        const int lr = e / NXI, c = e - lr * NXI;
        const float pn = mb - applyA(slabV, lr, c, gr0 + lr, cbmo, cbom);
        preg[k] = pn; rreg[k] = pn; r0reg[k] = pn;
        ureg[k] = 0.0f;
        slabP[(lr + 2) * NXI + c] = pn;
        if (lr == 0)  astoref(ghq_own + c, pn);
        if (lr == 1)  astoref(ghq_own + NXI + c, pn);
        if (lr == 10) astoref(ghq_own + 2 * NXI + c, pn);
        if (lr == 11) astoref(ghq_own + 3 * NXI + c, pn);
        pp += (double)pn * (double)pn;
      }
      bredN(&pp, 1, slots, 28 + par, sys, bs, tid);
      sys_bar(flags, &bphase, tid, bs);  // R2
      if (tid < 64) {
        double sp[1]; shredN(slots, 28 + par, 1, sys, lane, sp);
        const float ra = froguard(sp[0]);
        if (lane == 0) { bcf[3] = ra; sh_r0abs = ra; }
      } else {
        for (int g = tid - 64; g < 4 * NXI; g += NTHR - 64) {
          const int gi = g / NXI, c = g - gi * NXI;
          const int r = (gi < 2) ? gi - 2 : gi + 10;
          ugh[g] = 0.0f;
          if ((r < 0) ? (bs > 0) : (bs < BPS - 1)) {
            float pn;
            if (gi == 0)      pn = aloadf(ghq_sys + (size_t)(bs - 1) * 4 * NXI + 2 * NXI + c);
            else if (gi == 1) pn = aloadf(ghq_sys + (size_t)(bs - 1) * 4 * NXI + 3 * NXI + c);
            else if (gi == 2) pn = aloadf(ghq_sys + (size_t)(bs + 1) * 4 * NXI + c);
            else              pn = aloadf(ghq_sys + (size_t)(bs + 1) * 4 * NXI + NXI + c);
            slabP[(r + 2) * NXI + c] = pn;
            rgh[g] = pn;
          }
        }
      }
      continue;   // loop-top syncthreads publishes bc + slabs
    }

    const float alpha = bcf[0];
    if (code == 2) {
      // C3: x += alpha*p ; r = s (terminal: top breaks next round)
#pragma unroll
      for (int k = 0; k < EPT; k++) {
        xreg[k] = xreg[k] + alpha * preg[k];
        rreg[k] = rreg[k] - alpha * vreg[k];
      }
      continue;
    }

    // ---- main update: t = z - alpha*w; x,r,p,u own + ghost maintenance ----
    const float omega = bcf[1];
    const float beta  = bcf[2];
    for (int g = tid; g < 2 * NXI; g += NTHR) {      // w ghosts rows -1,12 (local)
      const bool top = g < NXI;
      if (top ? (bs > 0) : (bs < BPS - 1)) {
        const int c = top ? g : g - NXI;
        const int r = top ? -1 : 12;
        wgh[(top ? 1 : 2) * NXI + c] = applyA(slabV, r, c, gr0 + r, cbmo, cbom);
      }
    }
    __syncthreads();   // wgh writes visible before ghost maintenance
#pragma unroll
    for (int k = 0; k < EPT; k++) {
      const int e = tid + k * NTHR;
      const int lr = e / NXI, c = e - lr * NXI;
      const float sc = rreg[k] - alpha * vreg[k];
      xreg[k] = xreg[k] + alpha * preg[k] + omega * sc;
      const float tn = zreg[k] - alpha * wreg[k];
      const float rn = sc - omega * tn;
      const float pn = rn + beta * (preg[k] - omega * vreg[k]);
      rreg[k] = rn;
      preg[k] = pn;
      ureg[k] = beta * (vreg[k] - omega * wreg[k]);   // u for next iter's z
      slabP[(lr + 2) * NXI + c] = pn;
    }
    for (int g = tid; g < 4 * NXI; g += NTHR) {      // ghost rows -2,-1,12,13
      const int gi = g / NXI, c = g - gi * NXI;
      const int r = (gi < 2) ? gi - 2 : gi + 10;
      if ((r < 0) ? (bs > 0) : (bs < BPS - 1)) {
        const int ci = (r + 2) * NXI + c;
        const float vg = slabV[ci];
        const float wg = wgh[g];
        const float zg = vg - ugh[g];
        const float rg = rgh[g];
        const float sg = rg - alpha * vg;
        const float tg = zg - alpha * wg;
        const float rgn = sg - omega * tg;
        const float pgn = rgn + beta * (slabP[ci] - omega * vg);
        rgh[g] = rgn;
        ugh[g] = beta * (vg - omega * wg);
        slabP[ci] = pgn;
      }
    }
    // no barrier: next pass A reads only block-local LDS (loop-top syncthreads)
  }

  // final write-out of x
#pragma unroll
  for (int k = 0; k < EPT; k++) {
    xs[tid + k * NTHR] = xreg[k];
  }
}

extern "C" void kernel_launch(void* const* d_in, const int* in_sizes, int n_in,
                              void* d_out, int out_size, void* d_ws, size_t ws_size,
                              hipStream_t stream) {
  const float* V  = (const float*)d_in[0];
  const float* M1 = (const float*)d_in[1];
  const float* M2 = (const float*)d_in[2];
  float* xout = (float*)d_out;
  float* wsf  = (float*)d_ws;
  hipMemsetAsync(d_ws, 0, 4096, stream);
  bicg_kernel<<<dim3(NBLK), dim3(NTHR), 0, stream>>>(V, M1, M2, xout, wsf);
}